// Round 1
// baseline (1103.613 us; speedup 1.0000x reference)
//
#include <hip/hip_runtime.h>
#include <math.h>

#define N_FFT 2048
#define HOP 512
#define N_HARM 5
#define NBINS 1025   // n_fft/2 + 1
#define PI_D 3.14159265358979323846

// ---------------------------------------------------------------------------
// Setup kernel: twiddle table (1024 x float2, exp(-2*pi*i*k/2048)) and
// periodic Hann window (2048 floats), computed in double precision.
// Recomputed every launch (d_ws is re-poisoned before every timed call).
// ---------------------------------------------------------------------------
__global__ void hfe_setup_tables(float2* __restrict__ tw, float* __restrict__ win) {
    int i = blockIdx.x * blockDim.x + threadIdx.x;
    if (i < 1024) {
        double ang = -2.0 * PI_D * (double)i / 2048.0;
        tw[i] = make_float2((float)cos(ang), (float)sin(ang));
    }
    if (i < 2048) {
        double c = cos(2.0 * PI_D * (double)i / 2048.0);
        win[i] = (float)(0.5 * (1.0 - c));
    }
}

// ---------------------------------------------------------------------------
// Main kernel: one 256-thread block per STFT frame.
//   1. load 2048 samples (reflect pad), apply window, bit-reversed store to LDS
//   2. 11 radix-2 DIT stages in LDS (fp32, accurate twiddles)
//   3. block argmax over mag^2 for bins 0..1024 (tie -> lowest index)
//   4. threads 0..4 emit log10(|X[h*f0]| + 1e-10)
// ---------------------------------------------------------------------------
__launch_bounds__(256)
__global__ void hfe_kernel(const float* __restrict__ audio,
                           const float2* __restrict__ tw,
                           const float* __restrict__ win,
                           float* __restrict__ out,
                           int L, int T) {
    __shared__ float re[2048];
    __shared__ float im[2048];
    __shared__ float twr[1024];
    __shared__ float twi[1024];
    __shared__ float rval[256];
    __shared__ int   ridx[256];
    __shared__ int   s_f0;

    const int tid   = threadIdx.x;
    const int frame = blockIdx.x;
    const int b     = frame / T;
    const int t     = frame - b * T;
    const long base = (long)b * (long)L;
    const int start = t * HOP - (N_FFT / 2);   // reflect-padded window start

    // stage twiddles into LDS (broadcast table, L2-resident)
    for (int i = tid; i < 1024; i += 256) {
        float2 w = tw[i];
        twr[i] = w.x;
        twi[i] = w.y;
    }

    // load + reflect pad + window + bit-reverse
    for (int i = tid; i < 2048; i += 256) {
        int p = start + i;
        p = (p < 0) ? -p : p;
        p = (p >= L) ? (2 * L - 2 - p) : p;
        float v = audio[base + p] * win[i];
        int r = (int)(__brev((unsigned)i) >> 21);   // 11-bit reversal
        re[r] = v;
        im[r] = 0.0f;
    }
    __syncthreads();

    // 11 radix-2 DIT stages
    #pragma unroll 1
    for (int s = 1; s <= 11; ++s) {
        const int half   = 1 << (s - 1);
        const int tshift = 11 - s;
        for (int j = tid; j < 1024; j += 256) {
            const int k  = j & (half - 1);
            const int i1 = ((j >> (s - 1)) << s) + k;
            const int i2 = i1 + half;
            const float wr = twr[k << tshift];
            const float wi = twi[k << tshift];
            const float r2 = re[i2], q2 = im[i2];
            const float tr = wr * r2 - wi * q2;
            const float ti = wr * q2 + wi * r2;
            const float r1 = re[i1], q1 = im[i1];
            re[i2] = r1 - tr;  im[i2] = q1 - ti;
            re[i1] = r1 + tr;  im[i1] = q1 + ti;
        }
        __syncthreads();
    }

    // argmax over mag^2 (order-preserving vs |X|), tie -> lowest bin
    float best = -1.0f;
    int   bidx = 0;
    for (int k = tid; k < NBINS; k += 256) {
        float m2 = re[k] * re[k] + im[k] * im[k];
        if (m2 > best) { best = m2; bidx = k; }
    }
    rval[tid] = best;
    ridx[tid] = bidx;
    __syncthreads();
    for (int off = 128; off > 0; off >>= 1) {
        if (tid < off) {
            float ov = rval[tid + off];
            int   oi = ridx[tid + off];
            float mv = rval[tid];
            int   mi = ridx[tid];
            if (ov > mv || (ov == mv && oi < mi)) {
                rval[tid] = ov;
                ridx[tid] = oi;
            }
        }
        __syncthreads();
    }
    if (tid == 0) s_f0 = ridx[0];
    __syncthreads();

    if (tid < N_HARM) {
        int bin = s_f0 * (tid + 1);
        if (bin > N_FFT / 2) bin = N_FFT / 2;
        float e = sqrtf(re[bin] * re[bin] + im[bin] * im[bin]);
        out[((long)b * N_HARM + tid) * (long)T + t] = log10f(e + 1e-10f);
    }
}

// ---------------------------------------------------------------------------
extern "C" void kernel_launch(void* const* d_in, const int* in_sizes, int n_in,
                              void* d_out, int out_size, void* d_ws, size_t ws_size,
                              hipStream_t stream) {
    const float* audio = (const float*)d_in[0];
    float*       out   = (float*)d_out;

    const int L = 655360;                 // samples per batch row (reference)
    const int B = in_sizes[0] / L;        // 32
    const int T = 1 + L / HOP;            // 1281 frames

    float2* tw  = (float2*)d_ws;
    float*  win = (float*)((char*)d_ws + 1024 * sizeof(float2));

    hfe_setup_tables<<<8, 256, 0, stream>>>(tw, win);
    hfe_kernel<<<B * T, 256, 0, stream>>>(audio, tw, win, out, L, T);
}

// Round 5
// 277.772 us; speedup vs baseline: 3.9731x; 3.9731x over previous
//
#include <hip/hip_runtime.h>
#include <math.h>

#define HOP 512
#define N_HARM 5
#define PI_D 3.14159265358979323846

// LDS pad: +1 float per 32 -> every strided power-of-2 access becomes <=2-way
#define PAD(a) ((a) + ((a) >> 5))

// ---------------------------------------------------------------------------
// Setup: master twiddle table tw[k] = exp(-2*pi*i*k/2048), k=0..1023, and
// periodic Hann window (2048), both computed in double precision.
// ---------------------------------------------------------------------------
__global__ void hfe_setup_tables(float2* __restrict__ tw, float* __restrict__ win) {
    int i = blockIdx.x * blockDim.x + threadIdx.x;
    if (i < 1024) {
        double ang = -2.0 * PI_D * (double)i / 2048.0;
        tw[i] = make_float2((float)cos(ang), (float)sin(ang));
    }
    if (i < 2048) {
        double c = cos(2.0 * PI_D * (double)i / 2048.0);
        win[i] = (float)(0.5 * (1.0 - c));
    }
}

// ---------------------------------------------------------------------------
// One radix-4 Stockham DIF stage. 256 threads, one butterfly each.
// Reads are always SRC[tid + p*256] (contiguous, conflict-free).
// Writes at k + M*(4j + q), padded -> <=2-way.
// ---------------------------------------------------------------------------
#define STAGE(SR, SI, DR, DI, LOG2M, SHIFT, LAST)                              \
  {                                                                            \
    const int M_ = 1 << (LOG2M);                                               \
    const int j_ = tid >> (LOG2M);                                             \
    const int k_ = tid & (M_ - 1);                                             \
    const float ar = SR[PAD(tid)],       ai = SI[PAD(tid)];                    \
    const float br = SR[PAD(tid + 256)], bi = SI[PAD(tid + 256)];              \
    const float cr = SR[PAD(tid + 512)], ci = SI[PAD(tid + 512)];              \
    const float dr = SR[PAD(tid + 768)], di = SI[PAD(tid + 768)];              \
    const float t0r = ar + cr, t0i = ai + ci;                                  \
    const float t1r = ar - cr, t1i = ai - ci;                                  \
    const float t2r = br + dr, t2i = bi + di;                                  \
    const float t3r = bi - di, t3i = -(br - dr);      /* -i*(b-d) */           \
    const float u0r = t0r + t2r, u0i = t0i + t2i;                              \
    const float u1r = t1r + t3r, u1i = t1i + t3i;                              \
    const float u2r = t0r - t2r, u2i = t0i - t2i;                              \
    const float u3r = t1r - t3r, u3i = t1i - t3i;                              \
    const int ob = k_ + (j_ << ((LOG2M) + 2));                                 \
    if (LAST) {                                                                \
      DR[PAD(ob)]          = u0r; DI[PAD(ob)]          = u0i;                  \
      DR[PAD(ob + M_)]     = u1r; DI[PAD(ob + M_)]     = u1i;                  \
      DR[PAD(ob + 2 * M_)] = u2r; DI[PAD(ob + 2 * M_)] = u2i;                  \
      DR[PAD(ob + 3 * M_)] = u3r; DI[PAD(ob + 3 * M_)] = u3i;                  \
    } else {                                                                   \
      const int w1x = j_ << (SHIFT);                                           \
      const int w2x = j_ << ((SHIFT) + 1);                                     \
      const float w1r = twr[w1x], w1i = twi[w1x];                              \
      const float w2r = twr[w2x], w2i = twi[w2x];                              \
      const float w3r = w1r * w2r - w1i * w2i;                                 \
      const float w3i = w1r * w2i + w1i * w2r;                                 \
      DR[PAD(ob)]          = u0r;                     DI[PAD(ob)]          = u0i;                     \
      DR[PAD(ob + M_)]     = w1r * u1r - w1i * u1i;   DI[PAD(ob + M_)]     = w1r * u1i + w1i * u1r;   \
      DR[PAD(ob + 2 * M_)] = w2r * u2r - w2i * u2i;   DI[PAD(ob + 2 * M_)] = w2r * u2i + w2i * u2r;   \
      DR[PAD(ob + 3 * M_)] = w3r * u3r - w3i * u3i;   DI[PAD(ob + 3 * M_)] = w3r * u3i + w3i * u3r;   \
    }                                                                          \
    __syncthreads();                                                           \
  }

// ---------------------------------------------------------------------------
// One 256-thread block per STFT frame.
//  1. load 2048 windowed samples (reflect pad) packed as 1024 complex -> LDS
//  2. 1024-pt complex FFT: 5 radix-4 Stockham stages (A->B->A->B->A->B)
//  3. real-untwist to X[0..1024], mag^2 -> LDS
//  4. shuffle-based block argmax (tie -> lowest bin), 5 harmonic gathers
// ---------------------------------------------------------------------------
__launch_bounds__(256)
__global__ void hfe_kernel(const float* __restrict__ audio,
                           const float2* __restrict__ tw,
                           const float* __restrict__ win,
                           float* __restrict__ out,
                           int L, int T) {
    __shared__ float Ar[1056], Ai[1056], Br[1056], Bi[1056];
    __shared__ float twr[1024], twi[1024];
    __shared__ float wbest[4];
    __shared__ int   widx[4];
    __shared__ int   s_f0;

    const int tid   = threadIdx.x;
    const int frame = blockIdx.x;
    const int b     = frame / T;
    const int t     = frame - b * T;
    const long base = (long)b * (long)L;
    const int start = t * HOP - 1024;   // reflect-padded window start

    // stage master twiddles into LDS
    for (int i = tid; i < 1024; i += 256) {
        float2 w = tw[i];
        twr[i] = w.x;
        twi[i] = w.y;
    }

    // load + reflect + window, packed z[n] = xw[2n] + i*xw[2n+1], natural order
    for (int n = tid; n < 1024; n += 256) {
        const int i0 = 2 * n, i1 = 2 * n + 1;
        int p0 = start + i0;
        p0 = (p0 < 0) ? -p0 : p0;
        p0 = (p0 >= L) ? (2 * L - 2 - p0) : p0;
        int p1 = start + i1;
        p1 = (p1 < 0) ? -p1 : p1;
        p1 = (p1 >= L) ? (2 * L - 2 - p1) : p1;
        Ar[PAD(n)] = audio[base + p0] * win[i0];
        Ai[PAD(n)] = audio[base + p1] * win[i1];
    }
    __syncthreads();

    // 5 radix-4 Stockham stages: (l, m) = (256,1)(64,4)(16,16)(4,64)(1,256)
    STAGE(Ar, Ai, Br, Bi, 0, 1, false)
    STAGE(Br, Bi, Ar, Ai, 2, 3, false)
    STAGE(Ar, Ai, Br, Bi, 4, 5, false)
    STAGE(Br, Bi, Ar, Ai, 6, 7, false)
    STAGE(Ar, Ai, Br, Bi, 8, 9, true)
    // final Z (natural order) is in B

    // untwist: X[k] = Ze[k] + tw[k]*Zo[k]; store mag^2 in Ar[0..1024]
    float best = -1.0f;
    int   bidx = 0;
    #pragma unroll
    for (int p = 0; p < 4; ++p) {
        const int k  = tid + p * 256;
        const int km = (1024 - k) & 1023;
        const float zkr = Br[PAD(k)],  zki = Bi[PAD(k)];
        const float zmr = Br[PAD(km)], zmi = Bi[PAD(km)];
        const float zer = 0.5f * (zkr + zmr), zei = 0.5f * (zki - zmi);
        const float zor = 0.5f * (zki + zmi), zoi = 0.5f * (zmr - zkr);
        const float wr = twr[k], wi = twi[k];
        const float xr = zer + (wr * zor - wi * zoi);
        const float xi = zei + (wr * zoi + wi * zor);
        const float m2 = xr * xr + xi * xi;
        Ar[k] = m2;
        if (m2 > best) { best = m2; bidx = k; }
        if (k == 0) {
            // X[1024] = Ze[0] - Zo[0] = Re(Z0) - Im(Z0)  (purely real)
            const float xn = zer - zor;
            const float m2n = xn * xn;
            Ar[1024] = m2n;
            if (m2n > best) { best = m2n; bidx = 1024; }
        }
    }

    // wave-level argmax (64 lanes), tie -> lowest bin
    #pragma unroll
    for (int off = 32; off > 0; off >>= 1) {
        const float ov = __shfl_xor(best, off);
        const int   oi = __shfl_xor(bidx, off);
        if (ov > best || (ov == best && oi < bidx)) { best = ov; bidx = oi; }
    }
    const int wv = tid >> 6;
    if ((tid & 63) == 0) { wbest[wv] = best; widx[wv] = bidx; }
    __syncthreads();   // also covers Ar[] mag2 writes
    if (tid == 0) {
        float bb = wbest[0];
        int   bx = widx[0];
        #pragma unroll
        for (int w = 1; w < 4; ++w) {
            if (wbest[w] > bb || (wbest[w] == bb && widx[w] < bx)) {
                bb = wbest[w];
                bx = widx[w];
            }
        }
        s_f0 = bx;
    }
    __syncthreads();

    if (tid < N_HARM) {
        int bin = s_f0 * (tid + 1);
        if (bin > 1024) bin = 1024;
        const float e = sqrtf(Ar[bin]);
        out[((long)b * N_HARM + tid) * (long)T + t] = log10f(e + 1e-10f);
    }
}

// ---------------------------------------------------------------------------
extern "C" void kernel_launch(void* const* d_in, const int* in_sizes, int n_in,
                              void* d_out, int out_size, void* d_ws, size_t ws_size,
                              hipStream_t stream) {
    const float* audio = (const float*)d_in[0];
    float*       out   = (float*)d_out;

    const int L = 655360;                 // samples per batch row (reference)
    const int B = in_sizes[0] / L;        // 32
    const int T = 1 + L / HOP;            // 1281 frames

    float2* tw  = (float2*)d_ws;
    float*  win = (float*)((char*)d_ws + 1024 * sizeof(float2));

    hfe_setup_tables<<<8, 256, 0, stream>>>(tw, win);
    hfe_kernel<<<B * T, 256, 0, stream>>>(audio, tw, win, out, L, T);
}

// Round 6
// 227.676 us; speedup vs baseline: 4.8473x; 1.2200x over previous
//
#include <hip/hip_runtime.h>
#include <math.h>

#define HOP 512
#define N_HARM 5
#define PI_D 3.14159265358979323846

// pad: +1 float2 per 16 float2s (one 128B LDS row)
#define P2(a) ((a) + ((a) >> 4))

__device__ __forceinline__ float2 cmul(float2 a, float2 b) {
    return make_float2(a.x * b.x - a.y * b.y, a.x * b.y + a.y * b.x);
}
__device__ __forceinline__ float2 cadd(float2 a, float2 b) {
    return make_float2(a.x + b.x, a.y + b.y);
}
__device__ __forceinline__ float2 csub(float2 a, float2 b) {
    return make_float2(a.x - b.x, a.y - b.y);
}

// ---------------------------------------------------------------------------
// Setup: master twiddle table tw[k] = exp(-2*pi*i*k/2048), k=0..1023, and
// periodic Hann window (2048), both computed in double precision.
// ---------------------------------------------------------------------------
__global__ void hfe_setup_tables(float2* __restrict__ tw, float* __restrict__ win) {
    int i = blockIdx.x * blockDim.x + threadIdx.x;
    if (i < 1024) {
        double ang = -2.0 * PI_D * (double)i / 2048.0;
        tw[i] = make_float2((float)cos(ang), (float)sin(ang));
    }
    if (i < 2048) {
        double c = cos(2.0 * PI_D * (double)i / 2048.0);
        win[i] = (float)(0.5 * (1.0 - c));
    }
}

// ---------------------------------------------------------------------------
// One radix-4 Stockham DIF stage, float2-interleaved, twiddles from global.
// Reads SRC[tid + p*256] (contiguous). Writes k + M*(4j + q), padded.
// ---------------------------------------------------------------------------
#define STAGE(S, D, LOG2M, SHIFT, LAST)                                        \
  {                                                                            \
    const int M_ = 1 << (LOG2M);                                               \
    const int j_ = tid >> (LOG2M);                                             \
    const int k_ = tid & (M_ - 1);                                             \
    const float2 va = S[P2(tid)];                                              \
    const float2 vb = S[P2(tid + 256)];                                        \
    const float2 vc = S[P2(tid + 512)];                                        \
    const float2 vd = S[P2(tid + 768)];                                        \
    const float2 t0 = cadd(va, vc);                                            \
    const float2 t1 = csub(va, vc);                                            \
    const float2 t2 = cadd(vb, vd);                                            \
    const float2 t3 = make_float2(vb.y - vd.y, -(vb.x - vd.x)); /* -i(b-d) */  \
    const float2 u0 = cadd(t0, t2);                                            \
    const float2 u1 = cadd(t1, t3);                                            \
    const float2 u2 = csub(t0, t2);                                            \
    const float2 u3 = csub(t1, t3);                                            \
    const int ob = k_ + (j_ << ((LOG2M) + 2));                                 \
    if (LAST) {                                                                \
      D[P2(ob)]          = u0;                                                 \
      D[P2(ob + M_)]     = u1;                                                 \
      D[P2(ob + 2 * M_)] = u2;                                                 \
      D[P2(ob + 3 * M_)] = u3;                                                 \
    } else {                                                                   \
      const float2 w1 = tw[j_ << (SHIFT)];                                     \
      const float2 w2 = tw[j_ << ((SHIFT) + 1)];                               \
      const float2 w3 = cmul(w1, w2);                                          \
      D[P2(ob)]          = u0;                                                 \
      D[P2(ob + M_)]     = cmul(w1, u1);                                       \
      D[P2(ob + 2 * M_)] = cmul(w2, u2);                                       \
      D[P2(ob + 3 * M_)] = cmul(w3, u3);                                       \
    }                                                                          \
    __syncthreads();                                                           \
  }

// ---------------------------------------------------------------------------
// One 256-thread block per STFT frame.
//  1. load 2048 windowed samples (float4 fast path; reflect slow path for
//     t in {0,1,1279,1280}) packed as 1024 complex -> LDS (float2)
//  2. 1024-pt complex FFT: 5 radix-4 Stockham stages A->B->A->B->A->B
//  3. real-untwist to X[0..1024], mag^2 -> mag[] (aliases dead A buffer)
//  4. shuffle-based block argmax (tie -> lowest bin), 5 harmonic gathers
// ---------------------------------------------------------------------------
__launch_bounds__(256)
__global__ void hfe_kernel(const float* __restrict__ audio,
                           const float2* __restrict__ tw,
                           const float* __restrict__ win,
                           float* __restrict__ out,
                           int L, int T) {
    __shared__ float2 A[1088], B[1088];   // 1024 + pad
    __shared__ float wbest[4];
    __shared__ int   widx[4];
    __shared__ int   s_f0;
    float* mag = reinterpret_cast<float*>(A);   // A is dead after stage 5

    const int tid   = threadIdx.x;
    const int frame = blockIdx.x;
    const int b     = frame / T;
    const int t     = frame - b * T;
    const long base = (long)b * (long)L;
    const int start = t * HOP - 1024;   // reflect-padded window start

    if (start >= 0 && start + 2048 <= L) {
        // fast path: contiguous, 16B-aligned (start multiple of 512)
        const float4* a4 = reinterpret_cast<const float4*>(audio + base + start);
        const float4* w4 = reinterpret_cast<const float4*>(win);
        #pragma unroll
        for (int p = 0; p < 2; ++p) {
            const int f = tid + p * 256;       // float4 index, points 2f, 2f+1
            const float4 x = a4[f];
            const float4 w = w4[f];
            A[P2(2 * f)]     = make_float2(x.x * w.x, x.y * w.y);
            A[P2(2 * f + 1)] = make_float2(x.z * w.z, x.w * w.w);
        }
    } else {
        // slow path: reflect padding (4 of 1281 frames)
        for (int n = tid; n < 1024; n += 256) {
            const int i0 = 2 * n, i1 = 2 * n + 1;
            int p0 = start + i0;
            p0 = (p0 < 0) ? -p0 : p0;
            p0 = (p0 >= L) ? (2 * L - 2 - p0) : p0;
            int p1 = start + i1;
            p1 = (p1 < 0) ? -p1 : p1;
            p1 = (p1 >= L) ? (2 * L - 2 - p1) : p1;
            A[P2(n)] = make_float2(audio[base + p0] * win[i0],
                                   audio[base + p1] * win[i1]);
        }
    }
    __syncthreads();

    // 5 radix-4 Stockham stages: M = 1,4,16,64,256
    STAGE(A, B, 0, 1, false)
    STAGE(B, A, 2, 3, false)
    STAGE(A, B, 4, 5, false)
    STAGE(B, A, 6, 7, false)
    STAGE(A, B, 8, 9, true)
    // final Z (natural order) is in B; A is dead -> mag[] aliases it

    // untwist: X[k] = Ze[k] + tw[k]*Zo[k]; store mag^2
    float best = -1.0f;
    int   bidx = 0;
    #pragma unroll
    for (int p = 0; p < 4; ++p) {
        const int k  = tid + p * 256;
        const int km = (1024 - k) & 1023;
        const float2 zk = B[P2(k)];
        const float2 zm = B[P2(km)];
        const float zer = 0.5f * (zk.x + zm.x), zei = 0.5f * (zk.y - zm.y);
        const float zor = 0.5f * (zk.y + zm.y), zoi = 0.5f * (zm.x - zk.x);
        const float2 w = tw[k];
        const float xr = zer + (w.x * zor - w.y * zoi);
        const float xi = zei + (w.x * zoi + w.y * zor);
        const float m2 = xr * xr + xi * xi;
        mag[k] = m2;
        if (m2 > best) { best = m2; bidx = k; }
        if (k == 0) {
            // X[1024] = Ze[0] - Zo[0]  (purely real)
            const float xn = zer - zor;
            const float m2n = xn * xn;
            mag[1024] = m2n;
            if (m2n > best) { best = m2n; bidx = 1024; }
        }
    }

    // wave-level argmax (64 lanes), tie -> lowest bin
    #pragma unroll
    for (int off = 32; off > 0; off >>= 1) {
        const float ov = __shfl_xor(best, off);
        const int   oi = __shfl_xor(bidx, off);
        if (ov > best || (ov == best && oi < bidx)) { best = ov; bidx = oi; }
    }
    const int wv = tid >> 6;
    if ((tid & 63) == 0) { wbest[wv] = best; widx[wv] = bidx; }
    __syncthreads();   // also covers mag[] writes
    if (tid == 0) {
        float bb = wbest[0];
        int   bx = widx[0];
        #pragma unroll
        for (int w = 1; w < 4; ++w) {
            if (wbest[w] > bb || (wbest[w] == bb && widx[w] < bx)) {
                bb = wbest[w];
                bx = widx[w];
            }
        }
        s_f0 = bx;
    }
    __syncthreads();

    if (tid < N_HARM) {
        int bin = s_f0 * (tid + 1);
        if (bin > 1024) bin = 1024;
        const float e = sqrtf(mag[bin]);
        out[((long)b * N_HARM + tid) * (long)T + t] = log10f(e + 1e-10f);
    }
}

// ---------------------------------------------------------------------------
extern "C" void kernel_launch(void* const* d_in, const int* in_sizes, int n_in,
                              void* d_out, int out_size, void* d_ws, size_t ws_size,
                              hipStream_t stream) {
    const float* audio = (const float*)d_in[0];
    float*       out   = (float*)d_out;

    const int L = 655360;                 // samples per batch row (reference)
    const int B = in_sizes[0] / L;        // 32
    const int T = 1 + L / HOP;            // 1281 frames

    float2* tw  = (float2*)d_ws;
    float*  win = (float*)((char*)d_ws + 1024 * sizeof(float2));

    hfe_setup_tables<<<8, 256, 0, stream>>>(tw, win);
    hfe_kernel<<<B * T, 256, 0, stream>>>(audio, tw, win, out, L, T);
}